// Round 2
// baseline (722.878 us; speedup 1.0000x reference)
//
#include <hip/hip_runtime.h>
#include <cstddef>

// Problem constants
// x: (4, 512, 64, 64)  w_qkv: (1536, 512)  w_dw: (1536,1,5,5)  w_pw: (192,8,8)
// w_proj: (512, 1024)  bn_*: (512,)
// N = H*W = 4096, heads = 128, 24 ch/head (q 0:8 relu, k 8:16 relu, v 16:24)
//
// Workspace layout (192 MiB total — fits conservative ws_size):
//   qkv: 4*1536*4096*4 = 100663296 B at offset 0
//   y:   same size      at offset 100663296
// Attention output is written IN-PLACE into the dead k-channel slots
// (ch 8..15 of each head) of qkv/y after attn_stats has consumed them.
// vk stats (144 KB) live in d_out, which the final GEMM fully overwrites.

#define NPIX 4096
#define TD3 1536

// ---------------------------------------------------------------------------
// Tiled fp32 GEMM: C[m,n] = sum_k A[m,k] * B[k,n]
// 128x128 block tile, BK=16, 256 threads, 8x8 per thread (split-quadrant).
// A shared across batch; B,C offset by blockIdx.z. Used for qkv conv1x1.
// ---------------------------------------------------------------------------
__global__ __launch_bounds__(256) void gemm128(
    const float* __restrict__ A, const float* __restrict__ Bm,
    float* __restrict__ Cm, int M, int N, int K)
{
    __shared__ float As[16][132];   // [k][m], padded
    __shared__ float Bs[16][128];   // [k][n]

    const int tid = threadIdx.x;
    const int tx = tid & 15;
    const int ty = tid >> 4;
    const int nBase = blockIdx.x * 128;
    const int mBase = blockIdx.y * 128;
    Bm += (size_t)blockIdx.z * K * N;
    Cm += (size_t)blockIdx.z * M * N;

    const int arow = tid >> 2;            // 0..63
    const int acol = (tid & 3) << 2;      // 0,4,8,12
    const int brow = tid >> 5;            // 0..7
    const int bcol = (tid & 31) << 2;     // 0..124

    float acc[8][8];
#pragma unroll
    for (int i = 0; i < 8; ++i)
#pragma unroll
        for (int j = 0; j < 8; ++j) acc[i][j] = 0.f;

    const int KT = K >> 4;
    for (int kt = 0; kt < KT; ++kt) {
#pragma unroll
        for (int it = 0; it < 2; ++it) {
            int r = arow + it * 64;
            float4 a = *(const float4*)&A[(size_t)(mBase + r) * K + kt * 16 + acol];
            As[acol + 0][r] = a.x;
            As[acol + 1][r] = a.y;
            As[acol + 2][r] = a.z;
            As[acol + 3][r] = a.w;
        }
#pragma unroll
        for (int it = 0; it < 2; ++it) {
            int r = brow + it * 8;
            float4 b = *(const float4*)&Bm[(size_t)(kt * 16 + r) * N + nBase + bcol];
            *(float4*)&Bs[r][bcol] = b;
        }
        __syncthreads();

#pragma unroll
        for (int k = 0; k < 16; ++k) {
            float4 a0 = *(const float4*)&As[k][ty * 4];
            float4 a1 = *(const float4*)&As[k][64 + ty * 4];
            float4 b0 = *(const float4*)&Bs[k][tx * 4];
            float4 b1 = *(const float4*)&Bs[k][64 + tx * 4];
            float av[8] = {a0.x, a0.y, a0.z, a0.w, a1.x, a1.y, a1.z, a1.w};
            float bv[8] = {b0.x, b0.y, b0.z, b0.w, b1.x, b1.y, b1.z, b1.w};
#pragma unroll
            for (int i = 0; i < 8; ++i)
#pragma unroll
                for (int j = 0; j < 8; ++j)
                    acc[i][j] = fmaf(av[i], bv[j], acc[i][j]);
        }
        __syncthreads();
    }

#pragma unroll
    for (int i = 0; i < 8; ++i) {
        int row = mBase + ((i < 4) ? (ty * 4 + i) : (64 + ty * 4 + (i - 4)));
        float4 o0, o1;
        o0.x = acc[i][0]; o0.y = acc[i][1]; o0.z = acc[i][2]; o0.w = acc[i][3];
        o1.x = acc[i][4]; o1.y = acc[i][5]; o1.z = acc[i][6]; o1.w = acc[i][7];
        *(float4*)&Cm[(size_t)row * N + nBase + tx * 4] = o0;
        *(float4*)&Cm[(size_t)row * N + nBase + 64 + tx * 4] = o1;
    }
}

// ---------------------------------------------------------------------------
// Proj GEMM with gathered B rows + BN epilogue.
// M=512, N=4096, K=1024. B row c (=h*8+d) lives at channel h*24+8+d of
// qkv (h<64) or y (h>=64) — the attention output written in-place.
// ---------------------------------------------------------------------------
__global__ __launch_bounds__(256) void proj_gemm(
    const float* __restrict__ A, const float* __restrict__ qkv,
    const float* __restrict__ yy, float* __restrict__ Cm,
    const float* __restrict__ bn_g, const float* __restrict__ bn_b,
    const float* __restrict__ bn_m, const float* __restrict__ bn_v)
{
    __shared__ float As[16][132];
    __shared__ float Bs[16][128];

    const int tid = threadIdx.x;
    const int tx = tid & 15;
    const int ty = tid >> 4;
    const int nBase = blockIdx.x * 128;
    const int mBase = blockIdx.y * 128;
    const int K = 1024, N = 4096;
    const float* qkvB = qkv + (size_t)blockIdx.z * TD3 * NPIX;
    const float* yB   = yy  + (size_t)blockIdx.z * TD3 * NPIX;
    Cm += (size_t)blockIdx.z * 512 * NPIX;

    const int arow = tid >> 2;
    const int acol = (tid & 3) << 2;
    const int brow = tid >> 5;
    const int bcol = (tid & 31) << 2;

    float acc[8][8];
#pragma unroll
    for (int i = 0; i < 8; ++i)
#pragma unroll
        for (int j = 0; j < 8; ++j) acc[i][j] = 0.f;

    for (int kt = 0; kt < 64; ++kt) {
#pragma unroll
        for (int it = 0; it < 2; ++it) {
            int r = arow + it * 64;
            float4 a = *(const float4*)&A[(size_t)(mBase + r) * K + kt * 16 + acol];
            As[acol + 0][r] = a.x;
            As[acol + 1][r] = a.y;
            As[acol + 2][r] = a.z;
            As[acol + 3][r] = a.w;
        }
#pragma unroll
        for (int it = 0; it < 2; ++it) {
            int r = brow + it * 8;
            int c = kt * 16 + r;            // logical B row 0..1023
            int h = c >> 3, d = c & 7;
            const float* bp = (h < 64)
                ? qkvB + (size_t)(h * 24 + 8 + d) * NPIX
                : yB   + (size_t)((h - 64) * 24 + 8 + d) * NPIX;
            *(float4*)&Bs[r][bcol] = *(const float4*)&bp[nBase + bcol];
        }
        __syncthreads();

#pragma unroll
        for (int k = 0; k < 16; ++k) {
            float4 a0 = *(const float4*)&As[k][ty * 4];
            float4 a1 = *(const float4*)&As[k][64 + ty * 4];
            float4 b0 = *(const float4*)&Bs[k][tx * 4];
            float4 b1 = *(const float4*)&Bs[k][64 + tx * 4];
            float av[8] = {a0.x, a0.y, a0.z, a0.w, a1.x, a1.y, a1.z, a1.w};
            float bv[8] = {b0.x, b0.y, b0.z, b0.w, b1.x, b1.y, b1.z, b1.w};
#pragma unroll
            for (int i = 0; i < 8; ++i)
#pragma unroll
                for (int j = 0; j < 8; ++j)
                    acc[i][j] = fmaf(av[i], bv[j], acc[i][j]);
        }
        __syncthreads();
    }

#pragma unroll
    for (int i = 0; i < 8; ++i) {
        int row = mBase + ((i < 4) ? (ty * 4 + i) : (64 + ty * 4 + (i - 4)));
        float sc = bn_g[row] * rsqrtf(bn_v[row] + 1e-5f);
        float sh = bn_b[row] - bn_m[row] * sc;
        float4 o0, o1;
        o0.x = acc[i][0] * sc + sh; o0.y = acc[i][1] * sc + sh;
        o0.z = acc[i][2] * sc + sh; o0.w = acc[i][3] * sc + sh;
        o1.x = acc[i][4] * sc + sh; o1.y = acc[i][5] * sc + sh;
        o1.z = acc[i][6] * sc + sh; o1.w = acc[i][7] * sc + sh;
        *(float4*)&Cm[(size_t)row * NPIX + nBase + tx * 4] = o0;
        *(float4*)&Cm[(size_t)row * NPIX + nBase + 64 + tx * 4] = o1;
    }
}

// ---------------------------------------------------------------------------
// Fused depthwise 5x5 conv (pad 2) + per-group 8x8 mix.
// One block = (batch b, group g, 4 rows of H). 256 threads, 1 px/thread.
// ---------------------------------------------------------------------------
__global__ __launch_bounds__(256) void dwpw(
    const float* __restrict__ qkv, const float* __restrict__ w_dw,
    const float* __restrict__ w_pw, float* __restrict__ y)
{
    __shared__ float tile[8][8][68];   // [ch][row(4+4)][col(64+4)]
    __shared__ float wd[8][25];
    __shared__ float wp[64];

    const int tid = threadIdx.x;
    const int g = blockIdx.y;
    const int b = blockIdx.z;
    const int h0 = blockIdx.x * 4;
    const size_t cbase = (size_t)b * TD3 + g * 8;

    if (tid < 200) wd[tid / 25][tid % 25] = w_dw[(g * 8 + tid / 25) * 25 + tid % 25];
    if (tid >= 192) wp[tid - 192] = w_pw[g * 64 + (tid - 192)];

    // load 8 channels x 8 rows x 68 cols (with zero halo): 4352 = 17*256
#pragma unroll
    for (int it = 0; it < 17; ++it) {
        int idx = tid + it * 256;
        int ch = idx / 544;           // 544 = 8*68
        int rem = idx - ch * 544;
        int r = rem / 68;
        int cc = rem - r * 68;
        int gh = h0 + r - 2, gw = cc - 2;
        float v = 0.f;
        if (gh >= 0 && gh < 64 && gw >= 0 && gw < 64)
            v = qkv[(cbase + ch) * NPIX + gh * 64 + gw];
        tile[ch][r][cc] = v;
    }
    __syncthreads();

    const int r = tid >> 6;       // 0..3
    const int wc = tid & 63;      // 0..63
    float dwv[8];
#pragma unroll
    for (int i = 0; i < 8; ++i) {
        float s = 0.f;
#pragma unroll
        for (int di = 0; di < 5; ++di)
#pragma unroll
            for (int dj = 0; dj < 5; ++dj)
                s = fmaf(tile[i][r + di][wc + dj], wd[i][di * 5 + dj], s);
        dwv[i] = s;
    }
#pragma unroll
    for (int o = 0; o < 8; ++o) {
        float s = 0.f;
#pragma unroll
        for (int i = 0; i < 8; ++i) s = fmaf(dwv[i], wp[o * 8 + i], s);
        y[(cbase + o) * NPIX + (h0 + r) * 64 + wc] = s;
    }
}

// ---------------------------------------------------------------------------
// Attention stats: per (b,h) compute vk[9][8] = sum_n [v;1][d,n] * relu(k)[e,n]
// ---------------------------------------------------------------------------
__global__ __launch_bounds__(256) void attn_stats(
    const float* __restrict__ qkv, const float* __restrict__ yy,
    float* __restrict__ vkout)
{
    const int h = blockIdx.x;
    const int b = blockIdx.y;
    const float* src = (h < 64)
        ? qkv + ((size_t)b * TD3 + h * 24) * NPIX
        : yy  + ((size_t)b * TD3 + (h - 64) * 24) * NPIX;

    float acc[9][8];
#pragma unroll
    for (int d = 0; d < 9; ++d)
#pragma unroll
        for (int e = 0; e < 8; ++e) acc[d][e] = 0.f;

    for (int n = threadIdx.x; n < NPIX; n += 256) {
        float kr[8], vv[8];
#pragma unroll
        for (int e = 0; e < 8; ++e) kr[e] = fmaxf(src[(8 + e) * NPIX + n], 0.f);
#pragma unroll
        for (int d = 0; d < 8; ++d) vv[d] = src[(16 + d) * NPIX + n];
#pragma unroll
        for (int d = 0; d < 8; ++d)
#pragma unroll
            for (int e = 0; e < 8; ++e) acc[d][e] = fmaf(vv[d], kr[e], acc[d][e]);
#pragma unroll
        for (int e = 0; e < 8; ++e) acc[8][e] += kr[e];
    }

    __shared__ float part[4][72];
    const int lane = threadIdx.x & 63, wave = threadIdx.x >> 6;
#pragma unroll
    for (int i = 0; i < 72; ++i) {
        float v = acc[i / 8][i % 8];
#pragma unroll
        for (int off = 32; off; off >>= 1) v += __shfl_down(v, off, 64);
        if (lane == 0) part[wave][i] = v;
    }
    __syncthreads();
    if (threadIdx.x < 72) {
        float v = part[0][threadIdx.x] + part[1][threadIdx.x] +
                  part[2][threadIdx.x] + part[3][threadIdx.x];
        vkout[((size_t)b * 128 + h) * 72 + threadIdx.x] = v;
    }
}

// ---------------------------------------------------------------------------
// Attention apply: out[d,n] = (sum_e vk[d][e] rq[e,n]) / (sum_e vk[8][e] rq[e,n] + eps)
// Written IN-PLACE into the (dead) k-channel slots of the head's source buffer.
// Reads only q channels (0..7), writes only k channels (8..15) — no overlap.
// ---------------------------------------------------------------------------
__global__ __launch_bounds__(256) void attn_apply(
    float* __restrict__ qkv, float* __restrict__ yy,
    const float* __restrict__ vkin)
{
    const int h = blockIdx.y;
    const int b = blockIdx.z;
    const int n = blockIdx.x * 256 + threadIdx.x;

    __shared__ float vk[72];
    if (threadIdx.x < 72)
        vk[threadIdx.x] = vkin[((size_t)b * 128 + h) * 72 + threadIdx.x];
    __syncthreads();

    float* src = (h < 64)
        ? qkv + ((size_t)b * TD3 + h * 24) * NPIX
        : yy  + ((size_t)b * TD3 + (h - 64) * 24) * NPIX;

    float qr[8];
#pragma unroll
    for (int e = 0; e < 8; ++e) qr[e] = fmaxf(src[e * NPIX + n], 0.f);

    float den = 0.f;
#pragma unroll
    for (int e = 0; e < 8; ++e) den = fmaf(vk[64 + e], qr[e], den);
    float inv = 1.f / (den + 1e-15f);

#pragma unroll
    for (int d = 0; d < 8; ++d) {
        float num = 0.f;
#pragma unroll
        for (int e = 0; e < 8; ++e) num = fmaf(vk[d * 8 + e], qr[e], num);
        src[(8 + d) * NPIX + n] = num * inv;   // k-slot, dead after attn_stats
    }
}

// ---------------------------------------------------------------------------
extern "C" void kernel_launch(void* const* d_in, const int* in_sizes, int n_in,
                              void* d_out, int out_size, void* d_ws, size_t ws_size,
                              hipStream_t stream)
{
    (void)in_sizes; (void)n_in; (void)out_size; (void)ws_size;
    const float* x      = (const float*)d_in[0];
    const float* w_qkv  = (const float*)d_in[1];
    const float* w_dw   = (const float*)d_in[2];
    const float* w_pw   = (const float*)d_in[3];
    const float* w_proj = (const float*)d_in[4];
    const float* bn_g   = (const float*)d_in[5];
    const float* bn_b   = (const float*)d_in[6];
    const float* bn_m   = (const float*)d_in[7];
    const float* bn_v   = (const float*)d_in[8];
    float* out = (float*)d_out;

    char* ws = (char*)d_ws;
    float* qkv = (float*)(ws);                 // 100663296 B
    float* y   = (float*)(ws + 100663296);     // 100663296 B  (total 192 MiB)
    float* vk  = out;                          // 147456 B scratch; final GEMM
                                               // fully overwrites d_out after use

    // 1. qkv = w_qkv @ x   (M=1536, N=4096, K=512, batch 4)
    gemm128<<<dim3(32, 12, 4), 256, 0, stream>>>(w_qkv, x, qkv, 1536, 4096, 512);
    // 2. y = groupmix(dwconv5x5(qkv))
    dwpw<<<dim3(16, 192, 4), 256, 0, stream>>>(qkv, w_dw, w_pw, y);
    // 3. attention stats vk per (b,h)  (vk scratch lives in d_out)
    attn_stats<<<dim3(128, 4), 256, 0, stream>>>(qkv, y, vk);
    // 4. attention apply -> written into dead k-slots of qkv/y
    attn_apply<<<dim3(16, 128, 4), 256, 0, stream>>>(qkv, y, vk);
    // 5. out = BN(w_proj @ gathered_attn)  (M=512, N=4096, K=1024, batch 4)
    proj_gemm<<<dim3(32, 4, 4), 256, 0, stream>>>(w_proj, qkv, y, out,
                                                  bn_g, bn_b, bn_m, bn_v);
}

// Round 4
// 359.938 us; speedup vs baseline: 2.0083x; 2.0083x over previous
//
#include <hip/hip_runtime.h>
#include <cstddef>

// LiteMLA: qkv GEMM (split-fp16 MFMA, 3-pass) -> dwconv5x5+groupmix ->
// linear attention -> proj GEMM (split-A fp16 MFMA, 2-pass) + BN.
// B=4, C=512, H=W=64, N=4096, heads=128, 24 ch/head.
//
// Precision design: attention's relu(q)/relu(k) sign decisions amplify GEMM
// rounding (R3: bf16 1-pass -> absmax 0.07). Split fp16 (hi+lo) gives
// ~2^-22 rel GEMM error on qkv; proj is linear so split-A only suffices.
//
// Workspace (peak 229 MiB):
//   qkv fp32     100663296 @ 0
//   y   fp32     100663296 @ 100663296
//   x_t_h fp16    16777216 @ 201326592  (dead after qkv GEMM)
//   x_t_l fp16    16777216 @ 218103808  (dead after qkv GEMM)
//   attout fp16   33554432 @ 201326592  (overlays x_t after it's dead)
//   w_qkv_h/l     1572864*2 @ 234881024
//   w_proj_h/l    1048576*2 @ 238026752
// vk stats (144 KB) live in d_out (proj GEMM fully overwrites d_out after).

#define NPIX 4096
#define TD3 1536

typedef _Float16 f16;
typedef __attribute__((ext_vector_type(8))) _Float16 v8h;
typedef __attribute__((ext_vector_type(4))) float v4f;
typedef unsigned short ushort_t;

#define GLL16(g, l) __builtin_amdgcn_global_load_lds(                         \
    (const __attribute__((address_space(1))) unsigned int*)(g),               \
    (__attribute__((address_space(3))) unsigned int*)(l), 16, 0, 0)

// ---------------------------------------------------------------------------
// Split fp16 MFMA GEMM (m97 structure). Ah/Al (M x K) row-major fp16,
// Bh (and Bl if SPLITB) (N x K) row-major fp16, C (M x N) fp32.
// 128x128 tile, BK=32, 256 threads = 4 waves, each wave 64x64 via 4x4 grid
// of 16x16x32 MFMAs. C = Ah*Bh + Al*Bh (+ Ah*Bl if SPLITB). BN epilogue opt.
// ---------------------------------------------------------------------------
template <int SPLITB, int BN>
__global__ __launch_bounds__(256) void gemm_f16(
    const f16* __restrict__ Ah, const f16* __restrict__ Al,
    const f16* __restrict__ Bh, const f16* __restrict__ Bl,
    float* __restrict__ C, int M, int N, int K,
    const float* __restrict__ bn_g, const float* __restrict__ bn_b,
    const float* __restrict__ bn_m, const float* __restrict__ bn_v)
{
    __shared__ f16 AsH[128 * 32];
    __shared__ f16 AsL[128 * 32];
    __shared__ f16 BsH[128 * 32];
    __shared__ f16 BsL[SPLITB ? 128 * 32 : 64];

    const int tid  = threadIdx.x;
    const int lane = tid & 63;
    const int w    = tid >> 6;
    const int wm   = w >> 1, wn = w & 1;
    const int mBase = blockIdx.y * 128, nBase = blockIdx.x * 128;
    Bh += (size_t)blockIdx.z * N * K;
    if (SPLITB) Bl += (size_t)blockIdx.z * N * K;
    C  += (size_t)blockIdx.z * M * N;

    // staging: each 8 KB tile = 8 chunks of (64 lanes x 16 B); wave w does
    // chunks w*2, w*2+1 of every tile.
    const f16* gAh[2]; const f16* gAl[2]; const f16* gBh[2]; const f16* gBl[2];
    int ldsOff[2];
    #pragma unroll
    for (int p = 0; p < 2; ++p) {
        int off = (w * 2 + p) * 1024 + lane * 16;  // byte offset in tile
        int r  = off >> 6;                         // row (64 B = 32 f16 per row)
        int ci = (off & 63) >> 1;                  // f16 col index
        gAh[p] = Ah + (size_t)(mBase + r) * K + ci;
        gAl[p] = Al + (size_t)(mBase + r) * K + ci;
        gBh[p] = Bh + (size_t)(nBase + r) * K + ci;
        if (SPLITB) gBl[p] = Bl + (size_t)(nBase + r) * K + ci;
        ldsOff[p] = (w * 2 + p) * 512;             // f16 index of chunk base
    }

    v4f acc[4][4];
    #pragma unroll
    for (int i = 0; i < 4; ++i)
        #pragma unroll
        for (int j = 0; j < 4; ++j)
            acc[i][j] = (v4f){0.f, 0.f, 0.f, 0.f};

    const int kq = lane >> 4;      // k-chunk of 8
    const int rm = lane & 15;      // row within 16
    const int KT = K >> 5;
    for (int kt = 0; kt < KT; ++kt) {
        #pragma unroll
        for (int p = 0; p < 2; ++p) {
            GLL16(gAh[p] + kt * 32, &AsH[ldsOff[p]]);
            GLL16(gAl[p] + kt * 32, &AsL[ldsOff[p]]);
            GLL16(gBh[p] + kt * 32, &BsH[ldsOff[p]]);
            if (SPLITB) GLL16(gBl[p] + kt * 32, &BsL[ldsOff[p]]);
        }
        __syncthreads();

        v8h ah[4], al[4], bh[4], bl[4];
        #pragma unroll
        for (int i = 0; i < 4; ++i) {
            ah[i] = *(const v8h*)&AsH[(wm * 64 + i * 16 + rm) * 32 + kq * 8];
            al[i] = *(const v8h*)&AsL[(wm * 64 + i * 16 + rm) * 32 + kq * 8];
            bh[i] = *(const v8h*)&BsH[(wn * 64 + i * 16 + rm) * 32 + kq * 8];
            if (SPLITB)
                bl[i] = *(const v8h*)&BsL[(wn * 64 + i * 16 + rm) * 32 + kq * 8];
        }
        #pragma unroll
        for (int i = 0; i < 4; ++i)
            #pragma unroll
            for (int j = 0; j < 4; ++j) {
                acc[i][j] = __builtin_amdgcn_mfma_f32_16x16x32_f16(
                    ah[i], bh[j], acc[i][j], 0, 0, 0);
                acc[i][j] = __builtin_amdgcn_mfma_f32_16x16x32_f16(
                    al[i], bh[j], acc[i][j], 0, 0, 0);
                if (SPLITB)
                    acc[i][j] = __builtin_amdgcn_mfma_f32_16x16x32_f16(
                        ah[i], bl[j], acc[i][j], 0, 0, 0);
            }
        __syncthreads();
    }

    // epilogue: D row=(lane>>4)*4+reg, col=lane&15 (dtype-independent layout)
    const int rq = lane >> 4, cn = lane & 15;
    #pragma unroll
    for (int i = 0; i < 4; ++i) {
        #pragma unroll
        for (int rg = 0; rg < 4; ++rg) {
            int row = mBase + wm * 64 + i * 16 + rq * 4 + rg;
            float sc = 1.f, sh = 0.f;
            if (BN) {
                sc = bn_g[row] * rsqrtf(bn_v[row] + 1e-5f);
                sh = bn_b[row] - bn_m[row] * sc;
            }
            #pragma unroll
            for (int j = 0; j < 4; ++j) {
                int col = nBase + wn * 64 + j * 16 + cn;
                float v = acc[i][j][rg];
                C[(size_t)row * N + col] = BN ? (v * sc + sh) : v;
            }
        }
    }
}

// ---------------------------------------------------------------------------
// fp32 -> (fp16 hi, fp16 lo) elementwise. n4 = count/4.
// ---------------------------------------------------------------------------
__global__ __launch_bounds__(256) void cvt_split(
    const float* __restrict__ src, f16* __restrict__ dh, f16* __restrict__ dl,
    int n4)
{
    int i = blockIdx.x * 256 + threadIdx.x;
    if (i < n4) {
        float4 f = ((const float4*)src)[i];
        f16 h[4], l[4];
        float ff[4] = {f.x, f.y, f.z, f.w};
        #pragma unroll
        for (int q = 0; q < 4; ++q) {
            h[q] = (f16)ff[q];
            l[q] = (f16)(ff[q] - (float)h[q]);
        }
        *(uint2*)&dh[(size_t)i * 4] = *(uint2*)h;
        *(uint2*)&dl[(size_t)i * 4] = *(uint2*)l;
    }
}

// ---------------------------------------------------------------------------
// Transpose + split: x (b, c=512, n=4096) fp32 -> x_t_h/l (b, n, c) fp16.
// 64x64 tiles, 256 threads.
// ---------------------------------------------------------------------------
__global__ __launch_bounds__(256) void transp_split(
    const float* __restrict__ src, f16* __restrict__ dh, f16* __restrict__ dl)
{
    __shared__ float t[64][65];
    const int tid = threadIdx.x;
    const int n0 = blockIdx.x * 64, c0 = blockIdx.y * 64, b = blockIdx.z;

    const int row = tid >> 2;            // source channel within tile
    const int nn  = (tid & 3) * 16;      // 16 pixels per thread
    const float* sp = src + ((size_t)b * 512 + c0 + row) * NPIX + n0 + nn;
    #pragma unroll
    for (int q = 0; q < 4; ++q) {
        float4 f = *(const float4*)(sp + q * 4);
        t[row][nn + q * 4 + 0] = f.x;
        t[row][nn + q * 4 + 1] = f.y;
        t[row][nn + q * 4 + 2] = f.z;
        t[row][nn + q * 4 + 3] = f.w;
    }
    __syncthreads();

    const int nrow = tid >> 2;           // dst pixel within tile
    const int cc   = (tid & 3) * 16;     // 16 channels per thread
    f16 h[16], l[16];
    #pragma unroll
    for (int q = 0; q < 16; ++q) {
        float f = t[cc + q][nrow];
        h[q] = (f16)f;
        l[q] = (f16)(f - (float)h[q]);
    }
    size_t di = ((size_t)b * NPIX + n0 + nrow) * 512 + c0 + cc;
    *(uint4*)&dh[di] = *(uint4*)&h[0];
    *(uint4*)&dh[di + 8] = *(uint4*)&h[8];
    *(uint4*)&dl[di] = *(uint4*)&l[0];
    *(uint4*)&dl[di + 8] = *(uint4*)&l[8];
}

// ---------------------------------------------------------------------------
// Fused depthwise 5x5 conv (pad 2) + per-group 8x8 mix. (unchanged, proven)
// ---------------------------------------------------------------------------
__global__ __launch_bounds__(256) void dwpw(
    const float* __restrict__ qkv, const float* __restrict__ w_dw,
    const float* __restrict__ w_pw, float* __restrict__ y)
{
    __shared__ float tile[8][8][68];
    __shared__ float wd[8][25];
    __shared__ float wp[64];

    const int tid = threadIdx.x;
    const int g = blockIdx.y;
    const int b = blockIdx.z;
    const int h0 = blockIdx.x * 4;
    const size_t cbase = (size_t)b * TD3 + g * 8;

    if (tid < 200) wd[tid / 25][tid % 25] = w_dw[(g * 8 + tid / 25) * 25 + tid % 25];
    if (tid >= 192) wp[tid - 192] = w_pw[g * 64 + (tid - 192)];

    #pragma unroll
    for (int it = 0; it < 17; ++it) {
        int idx = tid + it * 256;
        int ch = idx / 544;
        int rem = idx - ch * 544;
        int r = rem / 68;
        int cc = rem - r * 68;
        int gh = h0 + r - 2, gw = cc - 2;
        float v = 0.f;
        if (gh >= 0 && gh < 64 && gw >= 0 && gw < 64)
            v = qkv[(cbase + ch) * NPIX + gh * 64 + gw];
        tile[ch][r][cc] = v;
    }
    __syncthreads();

    const int r = tid >> 6;
    const int wc = tid & 63;
    float dwv[8];
    #pragma unroll
    for (int i = 0; i < 8; ++i) {
        float s = 0.f;
        #pragma unroll
        for (int di = 0; di < 5; ++di)
            #pragma unroll
            for (int dj = 0; dj < 5; ++dj)
                s = fmaf(tile[i][r + di][wc + dj], wd[i][di * 5 + dj], s);
        dwv[i] = s;
    }
    #pragma unroll
    for (int o = 0; o < 8; ++o) {
        float s = 0.f;
        #pragma unroll
        for (int i = 0; i < 8; ++i) s = fmaf(dwv[i], wp[o * 8 + i], s);
        y[(cbase + o) * NPIX + (h0 + r) * 64 + wc] = s;
    }
}

// ---------------------------------------------------------------------------
// Attention stats per (b,h): vk[9][8] = sum_n [v;1][d,n] * relu(k)[e,n]
// ---------------------------------------------------------------------------
__global__ __launch_bounds__(256) void attn_stats(
    const float* __restrict__ qkv, const float* __restrict__ yy,
    float* __restrict__ vkout)
{
    const int h = blockIdx.x;
    const int b = blockIdx.y;
    const float* src = (h < 64)
        ? qkv + ((size_t)b * TD3 + h * 24) * NPIX
        : yy  + ((size_t)b * TD3 + (h - 64) * 24) * NPIX;

    float acc[9][8];
    #pragma unroll
    for (int d = 0; d < 9; ++d)
        #pragma unroll
        for (int e = 0; e < 8; ++e) acc[d][e] = 0.f;

    for (int n = threadIdx.x; n < NPIX; n += 256) {
        float kr[8], vv[8];
        #pragma unroll
        for (int e = 0; e < 8; ++e) kr[e] = fmaxf(src[(8 + e) * NPIX + n], 0.f);
        #pragma unroll
        for (int d = 0; d < 8; ++d) vv[d] = src[(16 + d) * NPIX + n];
        #pragma unroll
        for (int d = 0; d < 8; ++d)
            #pragma unroll
            for (int e = 0; e < 8; ++e) acc[d][e] = fmaf(vv[d], kr[e], acc[d][e]);
        #pragma unroll
        for (int e = 0; e < 8; ++e) acc[8][e] += kr[e];
    }

    __shared__ float part[4][72];
    const int lane = threadIdx.x & 63, wave = threadIdx.x >> 6;
    #pragma unroll
    for (int i = 0; i < 72; ++i) {
        float v = acc[i / 8][i % 8];
        #pragma unroll
        for (int off = 32; off; off >>= 1) v += __shfl_down(v, off, 64);
        if (lane == 0) part[wave][i] = v;
    }
    __syncthreads();
    if (threadIdx.x < 72) {
        float v = part[0][threadIdx.x] + part[1][threadIdx.x] +
                  part[2][threadIdx.x] + part[3][threadIdx.x];
        vkout[((size_t)b * 128 + h) * 72 + threadIdx.x] = v;
    }
}

// ---------------------------------------------------------------------------
// Attention apply: out[d,n] = (sum_e vk[d][e] rq[e]) / (sum_e vk[8][e] rq[e]+eps)
// Writes DIRECTLY transposed as fp16: attout[(b*4096+n)*1024 + h*8 + d].
// ---------------------------------------------------------------------------
__global__ __launch_bounds__(256) void attn_apply_t(
    const float* __restrict__ qkv, const float* __restrict__ yy,
    const float* __restrict__ vkin, f16* __restrict__ attout)
{
    const int h = blockIdx.y;
    const int b = blockIdx.z;
    const int n = blockIdx.x * 256 + threadIdx.x;

    __shared__ float vk[72];
    if (threadIdx.x < 72)
        vk[threadIdx.x] = vkin[((size_t)b * 128 + h) * 72 + threadIdx.x];
    __syncthreads();

    const float* src = (h < 64)
        ? qkv + ((size_t)b * TD3 + h * 24) * NPIX
        : yy  + ((size_t)b * TD3 + (h - 64) * 24) * NPIX;

    float qr[8];
    #pragma unroll
    for (int e = 0; e < 8; ++e) qr[e] = fmaxf(src[e * NPIX + n], 0.f);

    float den = 0.f;
    #pragma unroll
    for (int e = 0; e < 8; ++e) den = fmaf(vk[64 + e], qr[e], den);
    float inv = 1.f / (den + 1e-15f);

    f16 o[8];
    #pragma unroll
    for (int d = 0; d < 8; ++d) {
        float num = 0.f;
        #pragma unroll
        for (int e = 0; e < 8; ++e) num = fmaf(vk[d * 8 + e], qr[e], num);
        o[d] = (f16)(num * inv);
    }
    *(uint4*)&attout[((size_t)b * NPIX + n) * 1024 + h * 8] = *(uint4*)o;
}

// ---------------------------------------------------------------------------
extern "C" void kernel_launch(void* const* d_in, const int* in_sizes, int n_in,
                              void* d_out, int out_size, void* d_ws, size_t ws_size,
                              hipStream_t stream)
{
    (void)in_sizes; (void)n_in; (void)out_size; (void)ws_size;
    const float* x      = (const float*)d_in[0];
    const float* w_qkv  = (const float*)d_in[1];
    const float* w_dw   = (const float*)d_in[2];
    const float* w_pw   = (const float*)d_in[3];
    const float* w_proj = (const float*)d_in[4];
    const float* bn_g   = (const float*)d_in[5];
    const float* bn_b   = (const float*)d_in[6];
    const float* bn_m   = (const float*)d_in[7];
    const float* bn_v   = (const float*)d_in[8];
    float* out = (float*)d_out;

    char* ws = (char*)d_ws;
    float* qkv     = (float*)(ws);
    float* y       = (float*)(ws + 100663296);
    f16*   x_t_h   = (f16*)(ws + 201326592);    // dead after qkv GEMM
    f16*   x_t_l   = (f16*)(ws + 218103808);    // dead after qkv GEMM
    f16*   attout  = (f16*)(ws + 201326592);    // overlays x_t_h/l
    f16*   w_qkv_h = (f16*)(ws + 234881024);
    f16*   w_qkv_l = (f16*)(ws + 236453888);
    f16*   w_proj_h= (f16*)(ws + 238026752);
    f16*   w_proj_l= (f16*)(ws + 239075328);
    float* vk      = out;                        // scratch; proj overwrites

    // 0. split weights to fp16 hi/lo
    cvt_split<<<768, 256, 0, stream>>>(w_qkv, w_qkv_h, w_qkv_l, 196608);
    cvt_split<<<512, 256, 0, stream>>>(w_proj, w_proj_h, w_proj_l, 131072);
    // 1. x (b,c,n) -> x_t (b,n,c) fp16 hi/lo
    transp_split<<<dim3(64, 8, 4), 256, 0, stream>>>(x, x_t_h, x_t_l);
    // 2. qkv = w_qkv @ x  (M=1536,N=4096,K=512, batch 4), 3-pass split
    gemm_f16<1, 0><<<dim3(32, 12, 4), 256, 0, stream>>>(
        w_qkv_h, w_qkv_l, x_t_h, x_t_l, qkv, 1536, 4096, 512,
        nullptr, nullptr, nullptr, nullptr);
    // 3. y = groupmix(dwconv5x5(qkv))
    dwpw<<<dim3(16, 192, 4), 256, 0, stream>>>(qkv, w_dw, w_pw, y);
    // 4. attention stats -> vk (in d_out)
    attn_stats<<<dim3(128, 4), 256, 0, stream>>>(qkv, y, vk);
    // 5. attention apply -> attout (b,n,c) fp16 (overwrites dead x_t region)
    attn_apply_t<<<dim3(16, 128, 4), 256, 0, stream>>>(qkv, y, vk, attout);
    // 6. out = BN(w_proj @ attout)  (M=512,N=4096,K=1024, batch 4), 2-pass
    gemm_f16<0, 1><<<dim3(32, 4, 4), 256, 0, stream>>>(
        w_proj_h, w_proj_l, attout, nullptr, out, 512, 4096, 1024,
        bn_g, bn_b, bn_m, bn_v);
}